// Round 4
// baseline (284.525 us; speedup 1.0000x reference)
//
#include <hip/hip_runtime.h>
#include <cstdint>

#define EPSN 1e-12f
static constexpr int B_ROWS = 1024;
static constexpr int IN_DIM = 512;
static constexpr int OUT_DIM = 64000;

typedef __attribute__((ext_vector_type(8))) short bf16x8;
typedef __attribute__((ext_vector_type(4))) float f32x4;

__device__ __forceinline__ unsigned short f2bf(float f) {
  uint32_t u = __builtin_bit_cast(uint32_t, f);
  u += 0x7fffu + ((u >> 16) & 1u);   // round-to-nearest-even
  return (unsigned short)(u >> 16);
}

__device__ __forceinline__ float wave_sum(float v) {
#pragma unroll
  for (int off = 32; off; off >>= 1) v += __shfl_xor(v, off);
  return v;
}

__device__ __forceinline__ void async16(const void* g, void* l) {
  __builtin_amdgcn_global_load_lds((const __attribute__((address_space(1))) uint32_t*)g,
                                   (__attribute__((address_space(3))) uint32_t*)l, 16, 0, 0);
}

// --- kernel 1: x-prep (norms + bf16 cast) + fixdot from RAW W (no dependencies) ---
__global__ void prep_kernel(const float* __restrict__ X, const int* __restrict__ label,
                            const float* __restrict__ Wg, float* __restrict__ norms,
                            float* __restrict__ fixdot, unsigned short* __restrict__ xbf) {
  int lane = threadIdx.x & 63;
  int row = blockIdx.x * 4 + (threadIdx.x >> 6);
  const float* src = X + (size_t)row * IN_DIM + lane * 8;
  float4 a = *(const float4*)src;
  float4 b = *(const float4*)(src + 4);
  uint4 u;
  u.x = (uint32_t)f2bf(a.x) | ((uint32_t)f2bf(a.y) << 16);
  u.y = (uint32_t)f2bf(a.z) | ((uint32_t)f2bf(a.w) << 16);
  u.z = (uint32_t)f2bf(b.x) | ((uint32_t)f2bf(b.y) << 16);
  u.w = (uint32_t)f2bf(b.z) | ((uint32_t)f2bf(b.w) << 16);
  *(uint4*)(xbf + (size_t)row * IN_DIM + lane * 8) = u;
  float ssx = a.x * a.x;
  ssx = fmaf(a.y, a.y, ssx); ssx = fmaf(a.z, a.z, ssx); ssx = fmaf(a.w, a.w, ssx);
  ssx = fmaf(b.x, b.x, ssx); ssx = fmaf(b.y, b.y, ssx); ssx = fmaf(b.z, b.z, ssx);
  ssx = fmaf(b.w, b.w, ssx);
  int lab = label[row];
  const float* wsrc = Wg + (size_t)lab * IN_DIM + lane * 8;
  float4 wa = *(const float4*)wsrc, wb = *(const float4*)(wsrc + 4);
  float d = a.x * wa.x;
  d = fmaf(a.y, wa.y, d); d = fmaf(a.z, wa.z, d); d = fmaf(a.w, wa.w, d);
  d = fmaf(b.x, wb.x, d); d = fmaf(b.y, wb.y, d); d = fmaf(b.z, wb.z, d);
  d = fmaf(b.w, wb.w, d);
  float ssw = wa.x * wa.x;
  ssw = fmaf(wa.y, wa.y, ssw); ssw = fmaf(wa.z, wa.z, ssw); ssw = fmaf(wa.w, wa.w, ssw);
  ssw = fmaf(wb.x, wb.x, ssw); ssw = fmaf(wb.y, wb.y, ssw); ssw = fmaf(wb.z, wb.z, ssw);
  ssw = fmaf(wb.w, wb.w, ssw);
  ssx = wave_sum(ssx);
  d = wave_sum(d);
  ssw = wave_sum(ssw);
  if (lane == 0) {
    norms[row] = sqrtf(ssx);
    fixdot[row] = d / fmaxf(sqrtf(ssw), EPSN);   // = x . wn[lab], exact f32
  }
}

// --- kernel 2: FUSED weight-normalize + bf16 MFMA GEMM + margin epilogue ---
// BM=BN=256, 8 waves (2Mx4N), per-wave C = 128x64, 16 sub-stages of K=32.
// Stage 0: panel row-norms -> invn[] in LDS; mT-share of wn f32 output written.
// K-loop: A (xbf, cache-resident) via global_load_lds ring-4 depth-3 counted
// vmcnt; B staged by re-reading W f32 (L2-warm), scaling by invn, ds_write
// swizzled bf16 (write-side swizzle matches read-side, both under our control).
__global__ __launch_bounds__(512, 2) void fused_kernel(
    const float* __restrict__ Wg, const unsigned short* __restrict__ Abf,
    const float* __restrict__ norms, const float* __restrict__ fixdot,
    const int* __restrict__ label, const float* __restrict__ mArr,
    float* __restrict__ out0, float* __restrict__ wnOut) {
  __shared__ char smem[132096];  // A ring 4x16K @0; B ring 4x16K @65536; invn @131072
  float* invnL = (float*)(smem + 131072);

  const int t = threadIdx.x;
  int flat = blockIdx.x;          // 1000 = 8 * 125, bijective XCD swizzle
  int xcd = flat & 7;
  int wk = (flat >> 3) + xcd * 125;
  int mT = wk & 3, nT = wk >> 2;  // 4 mT siblings per nT are consecutive on one XCD
  int rowA0 = mT * 256, rowB0 = nT * 256;

  int lane = t & 63;
  int wid = t >> 6;
  int wm = wid >> 2, wn2 = wid & 3;   // 2M x 4N wave grid
  int rl = lane & 15, sl = lane >> 4;

  // ---- stage 0: B-panel row norms; distributed wn f32 write (each mT 1/4) ----
#pragma unroll 1
  for (int rr = 0; rr < 32; ++rr) {
    int r = wid * 32 + rr;
    const float* src = Wg + (size_t)(rowB0 + r) * IN_DIM + lane * 8;
    float4 a = *(const float4*)src;
    float4 b = *(const float4*)(src + 4);
    float ss = a.x * a.x;
    ss = fmaf(a.y, a.y, ss); ss = fmaf(a.z, a.z, ss); ss = fmaf(a.w, a.w, ss);
    ss = fmaf(b.x, b.x, ss); ss = fmaf(b.y, b.y, ss); ss = fmaf(b.z, b.z, ss);
    ss = fmaf(b.w, b.w, ss);
    ss = wave_sum(ss);
    float inv = 1.0f / fmaxf(sqrtf(ss), EPSN);
    if (lane == 0) invnL[r] = inv;
    if ((r >> 6) == mT) {           // this block's quarter of the wn output
      float* dst = wnOut + (size_t)(rowB0 + r) * IN_DIM + lane * 8;
      float4 wa, wb;
      wa.x = a.x * inv; wa.y = a.y * inv; wa.z = a.z * inv; wa.w = a.w * inv;
      wb.x = b.x * inv; wb.y = b.y * inv; wb.z = b.z * inv; wb.w = b.w * inv;
      *(float4*)dst = wa;
      *(float4*)(dst + 4) = wb;
    }
  }
  __syncthreads();

  // per-thread B chunk map (2 chunks c = t, t+512): row r = c>>2, 16B-slot q = c&3
  int r0 = t >> 2, q0 = t & 3;
  int r1 = (t + 512) >> 2, q1 = (t + 512) & 3;
  float inv0 = invnL[r0], inv1 = invnL[r1];
  const float* bSrc0 = Wg + (size_t)(rowB0 + r0) * IN_DIM + q0 * 8;
  const float* bSrc1 = Wg + (size_t)(rowB0 + r1) * IN_DIM + q1 * 8;
  int bOff0 = r0 * 64 + ((q0 ^ ((r0 >> 1) & 3)) * 16);
  int bOff1 = r1 * 64 + ((q1 ^ ((r1 >> 1) & 3)) * 16);

  // A staging map: inverse-swizzled global source, linear LDS dest (rule #21)
  int ra0 = t >> 2, qa0 = (t & 3) ^ ((ra0 >> 1) & 3);
  int ra1 = (t + 512) >> 2, qa1 = ((t + 512) & 3) ^ ((ra1 >> 1) & 3);
  const unsigned short* aP0 = Abf + (size_t)(rowA0 + ra0) * IN_DIM + qa0 * 8;
  const unsigned short* aP1 = Abf + (size_t)(rowA0 + ra1) * IN_DIM + qa1 * 8;

  auto issueA = [&](int sig) {
    char* aD = smem + (sig & 3) * 16384;
    int kcol = sig * 32;
    async16(aP0 + kcol, aD + t * 16);
    async16(aP1 + kcol, aD + (t + 512) * 16);
  };
  auto stageB = [&](int sig) {
    char* bD = smem + 65536 + (sig & 3) * 16384;
    int kcol = sig * 32;
    float4 f0 = *(const float4*)(bSrc0 + kcol);
    float4 f1 = *(const float4*)(bSrc0 + kcol + 4);
    uint4 u;
    u.x = (uint32_t)f2bf(f0.x * inv0) | ((uint32_t)f2bf(f0.y * inv0) << 16);
    u.y = (uint32_t)f2bf(f0.z * inv0) | ((uint32_t)f2bf(f0.w * inv0) << 16);
    u.z = (uint32_t)f2bf(f1.x * inv0) | ((uint32_t)f2bf(f1.y * inv0) << 16);
    u.w = (uint32_t)f2bf(f1.z * inv0) | ((uint32_t)f2bf(f1.w * inv0) << 16);
    *(uint4*)(bD + bOff0) = u;
    f0 = *(const float4*)(bSrc1 + kcol);
    f1 = *(const float4*)(bSrc1 + kcol + 4);
    u.x = (uint32_t)f2bf(f0.x * inv1) | ((uint32_t)f2bf(f0.y * inv1) << 16);
    u.y = (uint32_t)f2bf(f0.z * inv1) | ((uint32_t)f2bf(f0.w * inv1) << 16);
    u.z = (uint32_t)f2bf(f1.x * inv1) | ((uint32_t)f2bf(f1.y * inv1) << 16);
    u.w = (uint32_t)f2bf(f1.z * inv1) | ((uint32_t)f2bf(f1.w * inv1) << 16);
    *(uint4*)(bD + bOff1) = u;
  };

  // prologue: A subs 0..2 in flight; B sub 0 written
  issueA(0); issueA(1); issueA(2);
  stageB(0);
  asm volatile("s_waitcnt lgkmcnt(0)" ::: "memory");

  f32x4 acc[8][4];
#pragma unroll
  for (int m = 0; m < 8; ++m)
#pragma unroll
    for (int n = 0; n < 4; ++n) acc[m][n] = (f32x4){0.f, 0.f, 0.f, 0.f};

#pragma unroll 1
  for (int sigma = 0; sigma < 16; ++sigma) {
    // start of phase: A(sigma) landed (B f32 loads always drained in-phase, so
    // vmcnt here counts only A-lds: subs sigma..min(sigma+2,15), 2 instr each)
    __builtin_amdgcn_sched_barrier(0);
    if (sigma <= 13)      asm volatile("s_waitcnt vmcnt(4)" ::: "memory");
    else if (sigma == 14) asm volatile("s_waitcnt vmcnt(2)" ::: "memory");
    else                  asm volatile("s_waitcnt vmcnt(0)" ::: "memory");
    __builtin_amdgcn_s_barrier();
    __builtin_amdgcn_sched_barrier(0);

    const char* aB = smem + (sigma & 3) * 16384;
    const char* bB = smem + 65536 + (sigma & 3) * 16384;
    bf16x8 av[8], bv[4];
#pragma unroll
    for (int m = 0; m < 8; ++m) {
      int r = wm * 128 + m * 16 + rl;
      av[m] = *(const bf16x8*)(aB + r * 64 + ((sl ^ ((r >> 1) & 3)) * 16));
    }
#pragma unroll
    for (int n = 0; n < 4; ++n) {
      int r = wn2 * 64 + n * 16 + rl;
      bv[n] = *(const bf16x8*)(bB + r * 64 + ((sl ^ ((r >> 1) & 3)) * 16));
    }
    if (sigma + 3 <= 15) issueA(sigma + 3);
    if (sigma + 1 <= 15) stageB(sigma + 1);   // L2-warm; ds_write slot (sigma+1)&3
    __builtin_amdgcn_s_setprio(1);
#pragma unroll
    for (int n = 0; n < 4; ++n)
#pragma unroll
      for (int m = 0; m < 8; ++m)
        acc[m][n] = __builtin_amdgcn_mfma_f32_16x16x32_bf16(av[m], bv[n], acc[m][n], 0, 0, 0);
    __builtin_amdgcn_s_setprio(0);
    // drain ds ops (reads of this phase + B writes for next) then barrier
    asm volatile("s_waitcnt lgkmcnt(0)" ::: "memory");
    __builtin_amdgcn_s_barrier();
    __builtin_amdgcn_sched_barrier(0);
  }

  // epilogue: out = rawdot, except at (r, label[r]) where the exact f32 dot decides
  float mm = mArr[0];
  float cm = cosf(mm), sm = sinf(mm);
  int rowb = rowA0 + wm * 128, colb = rowB0 + wn2 * 64;
#pragma unroll
  for (int m = 0; m < 8; ++m) {
#pragma unroll
    for (int q = 0; q < 4; ++q) {
      int R = rowb + m * 16 + sl * 4 + q;
      int lab = label[R];
      float nv = norms[R], fv = fixdot[R];
      float* orow = out0 + (size_t)R * OUT_DIM;
#pragma unroll
      for (int n = 0; n < 4; ++n) {
        int Cc = colb + n * 16 + rl;
        float val = acc[m][n][q];
        if (Cc == lab) {
          float c = fv / fmaxf(nv, EPSN);
          val = (c > 0.f) ? nv * (c * cm - sqrtf(fmaxf(1.f - c * c, 0.f)) * sm) : fv;
        }
        orow[Cc] = val;
      }
    }
  }
}

extern "C" void kernel_launch(void* const* d_in, const int* in_sizes, int n_in,
                              void* d_out, int out_size, void* d_ws, size_t ws_size,
                              hipStream_t stream) {
  const float* x = (const float*)d_in[0];
  const int* label = (const int*)d_in[1];
  const float* weight = (const float*)d_in[2];
  const float* mArr = (const float*)d_in[4];  // d_in[3] = s, unused by normfree output

  float* out0 = (float*)d_out;                               // [1024, 64000]
  float* wnOut = out0 + (size_t)B_ROWS * OUT_DIM;            // [64000, 512]

  char* ws = (char*)d_ws;
  float* norms = (float*)ws;                                 // 4 KiB
  float* fixdot = (float*)(ws + 4096);                       // 4 KiB
  unsigned short* xbf = (unsigned short*)(ws + 8192);        // 1 MiB

  prep_kernel<<<B_ROWS / 4, 256, 0, stream>>>(x, label, weight, norms, fixdot, xbf);
  fused_kernel<<<1000, 512, 0, stream>>>(weight, xbf, norms, fixdot, label, mArr,
                                         out0, wnOut);
}

// Round 5
// 229.992 us; speedup vs baseline: 1.2371x; 1.2371x over previous
//
#include <hip/hip_runtime.h>
#include <cstdint>

#define EPSN 1e-12f
static constexpr int B_ROWS = 1024;
static constexpr int IN_DIM = 512;
static constexpr int OUT_DIM = 64000;

typedef __attribute__((ext_vector_type(8))) short bf16x8;
typedef __attribute__((ext_vector_type(4))) float f32x4;

__device__ __forceinline__ unsigned short f2bf(float f) {
  uint32_t u = __builtin_bit_cast(uint32_t, f);
  u += 0x7fffu + ((u >> 16) & 1u);   // round-to-nearest-even
  return (unsigned short)(u >> 16);
}

__device__ __forceinline__ float bf2f(unsigned short h) {
  uint32_t u = (uint32_t)h << 16;
  return __builtin_bit_cast(float, u);
}

__device__ __forceinline__ float wave_sum(float v) {
#pragma unroll
  for (int off = 32; off; off >>= 1) v += __shfl_xor(v, off);
  return v;
}

__device__ __forceinline__ void async16(const void* g, void* l) {
  __builtin_amdgcn_global_load_lds((const __attribute__((address_space(1))) uint32_t*)g,
                                   (__attribute__((address_space(3))) uint32_t*)l, 16, 0, 0);
}

// --- kernel 1: x-prep (norms + bf16 cast) + exact fixdot from RAW W ---
__global__ void prep_kernel(const float* __restrict__ X, const int* __restrict__ label,
                            const float* __restrict__ Wg, float* __restrict__ norms,
                            float* __restrict__ fixdot, unsigned short* __restrict__ xbf) {
  int lane = threadIdx.x & 63;
  int row = blockIdx.x * 4 + (threadIdx.x >> 6);
  const float* src = X + (size_t)row * IN_DIM + lane * 8;
  float4 a = *(const float4*)src;
  float4 b = *(const float4*)(src + 4);
  uint4 u;
  u.x = (uint32_t)f2bf(a.x) | ((uint32_t)f2bf(a.y) << 16);
  u.y = (uint32_t)f2bf(a.z) | ((uint32_t)f2bf(a.w) << 16);
  u.z = (uint32_t)f2bf(b.x) | ((uint32_t)f2bf(b.y) << 16);
  u.w = (uint32_t)f2bf(b.z) | ((uint32_t)f2bf(b.w) << 16);
  *(uint4*)(xbf + (size_t)row * IN_DIM + lane * 8) = u;
  float ssx = a.x * a.x;
  ssx = fmaf(a.y, a.y, ssx); ssx = fmaf(a.z, a.z, ssx); ssx = fmaf(a.w, a.w, ssx);
  ssx = fmaf(b.x, b.x, ssx); ssx = fmaf(b.y, b.y, ssx); ssx = fmaf(b.z, b.z, ssx);
  ssx = fmaf(b.w, b.w, ssx);
  int lab = label[row];
  const float* wsrc = Wg + (size_t)lab * IN_DIM + lane * 8;
  float4 wa = *(const float4*)wsrc, wb = *(const float4*)(wsrc + 4);
  float d = a.x * wa.x;
  d = fmaf(a.y, wa.y, d); d = fmaf(a.z, wa.z, d); d = fmaf(a.w, wa.w, d);
  d = fmaf(b.x, wb.x, d); d = fmaf(b.y, wb.y, d); d = fmaf(b.z, wb.z, d);
  d = fmaf(b.w, wb.w, d);
  float ssw = wa.x * wa.x;
  ssw = fmaf(wa.y, wa.y, ssw); ssw = fmaf(wa.z, wa.z, ssw); ssw = fmaf(wa.w, wa.w, ssw);
  ssw = fmaf(wb.x, wb.x, ssw); ssw = fmaf(wb.y, wb.y, ssw); ssw = fmaf(wb.z, wb.z, ssw);
  ssw = fmaf(wb.w, wb.w, ssw);
  ssx = wave_sum(ssx);
  d = wave_sum(d);
  ssw = wave_sum(ssw);
  if (lane == 0) {
    norms[row] = sqrtf(ssx);
    fixdot[row] = d / fmaxf(sqrtf(ssw), EPSN);   // = x . wn[lab], exact f32
  }
}

// --- kernel 2: W -> normalized bf16 (wbf) only. wn f32 output is written by
// the GEMM epilogue (bf16-rounded, error << threshold). 196 MB traffic. ---
__global__ void wcast_kernel(const float* __restrict__ Wg, unsigned short* __restrict__ wbf) {
  int lane = threadIdx.x & 63;
  int row = blockIdx.x * 4 + (threadIdx.x >> 6);
  const float* src = Wg + (size_t)row * IN_DIM + lane * 8;
  float4 a = *(const float4*)src;
  float4 b = *(const float4*)(src + 4);
  float ss = a.x * a.x;
  ss = fmaf(a.y, a.y, ss); ss = fmaf(a.z, a.z, ss); ss = fmaf(a.w, a.w, ss);
  ss = fmaf(b.x, b.x, ss); ss = fmaf(b.y, b.y, ss); ss = fmaf(b.z, b.z, ss);
  ss = fmaf(b.w, b.w, ss);
  ss = wave_sum(ss);
  float inv = 1.0f / fmaxf(sqrtf(ss), EPSN);
  uint4 u;
  u.x = (uint32_t)f2bf(a.x * inv) | ((uint32_t)f2bf(a.y * inv) << 16);
  u.y = (uint32_t)f2bf(a.z * inv) | ((uint32_t)f2bf(a.w * inv) << 16);
  u.z = (uint32_t)f2bf(b.x * inv) | ((uint32_t)f2bf(b.y * inv) << 16);
  u.w = (uint32_t)f2bf(b.z * inv) | ((uint32_t)f2bf(b.w * inv) << 16);
  *(uint4*)(wbf + (size_t)row * IN_DIM + lane * 8) = u;
}

// --- kernel 3: bf16 MFMA GEMM (M=1024,N=64000,K=512) + margin epilogue + wn write ---
// BM=BN=128, 8 waves (4Mx2N), per-wave C = 32x64 (acc[2][4]). 16 K-subs of 32.
// Ring-4 LDS (A 4x8K @0, B 4x8K @32768) = 64 KiB -> 2 blocks/CU. Depth-3
// counted vmcnt (2 gload_lds per sub): wait 4/4/2/0; issue sub sigma+3 after
// ds_reads; lgkmcnt(0)+barrier at phase end guards ring slot reuse (R3 proof).
__global__ __launch_bounds__(512, 2) void gemm_epi_kernel(
    const unsigned short* __restrict__ Abf, const unsigned short* __restrict__ Bbf,
    const float* __restrict__ norms, const float* __restrict__ fixdot,
    const int* __restrict__ label, const float* __restrict__ mArr,
    float* __restrict__ out0, float* __restrict__ wnOut) {
  __shared__ char smem[65536];

  const int t = threadIdx.x;
  int flat = blockIdx.x;          // 4000 = 8 * 500, bijective XCD swizzle
  int xcd = flat & 7;
  int wk = (flat >> 3) + xcd * 500;
  int mT = wk & 7, nT = wk >> 3;  // 8 mT siblings per nT consecutive on one XCD
  int rowA0 = mT * 128, rowB0 = nT * 128;

  int lane = t & 63;
  int wid = t >> 6;
  int wm = wid >> 1, wn2 = wid & 1;   // 4M x 2N wave grid
  int rl = lane & 15, sl = lane >> 4;

  // staging map (inverse swizzle): chunk c = t -> row r = c>>2, 16B-slot q
  int r0 = t >> 2, q0 = (t & 3) ^ ((r0 >> 1) & 3);
  const unsigned short* aP = Abf + (size_t)(rowA0 + r0) * IN_DIM + q0 * 8;
  const unsigned short* bP = Bbf + (size_t)(rowB0 + r0) * IN_DIM + q0 * 8;

  auto issueSub = [&](int sig) {
    int kcol = sig * 32;
    char* aD = smem + (sig & 3) * 8192;
    char* bD = smem + 32768 + (sig & 3) * 8192;
    async16(aP + kcol, aD + t * 16);
    async16(bP + kcol, bD + t * 16);
  };

  issueSub(0); issueSub(1); issueSub(2);   // depth-3 prologue (6 outstanding)

  f32x4 acc[2][4];
#pragma unroll
  for (int m = 0; m < 2; ++m)
#pragma unroll
    for (int n = 0; n < 4; ++n) acc[m][n] = (f32x4){0.f, 0.f, 0.f, 0.f};

#pragma unroll 1
  for (int sigma = 0; sigma < 16; ++sigma) {
    __builtin_amdgcn_sched_barrier(0);
    if (sigma <= 13)      asm volatile("s_waitcnt vmcnt(4)" ::: "memory");
    else if (sigma == 14) asm volatile("s_waitcnt vmcnt(2)" ::: "memory");
    else                  asm volatile("s_waitcnt vmcnt(0)" ::: "memory");
    __builtin_amdgcn_s_barrier();
    __builtin_amdgcn_sched_barrier(0);

    const char* aB = smem + (sigma & 3) * 8192;
    const char* bB = smem + 32768 + (sigma & 3) * 8192;
    bf16x8 av[2], bv[4];
#pragma unroll
    for (int m = 0; m < 2; ++m) {
      int r = wm * 32 + m * 16 + rl;
      av[m] = *(const bf16x8*)(aB + r * 64 + ((sl ^ ((r >> 1) & 3)) * 16));
    }
#pragma unroll
    for (int n = 0; n < 4; ++n) {
      int r = wn2 * 64 + n * 16 + rl;
      bv[n] = *(const bf16x8*)(bB + r * 64 + ((sl ^ ((r >> 1) & 3)) * 16));
    }
    if (sigma + 3 <= 15) issueSub(sigma + 3);
    __builtin_amdgcn_s_setprio(1);
#pragma unroll
    for (int n = 0; n < 4; ++n)
#pragma unroll
      for (int m = 0; m < 2; ++m)
        acc[m][n] = __builtin_amdgcn_mfma_f32_16x16x32_bf16(av[m], bv[n], acc[m][n], 0, 0, 0);
    __builtin_amdgcn_s_setprio(0);
    asm volatile("s_waitcnt lgkmcnt(0)" ::: "memory");
    __builtin_amdgcn_s_barrier();
    __builtin_amdgcn_sched_barrier(0);
  }

  // ---- wn f32 output: this block writes 16 rows of panel nT (mT-distributed),
  // converted from L2-hot wbf (bf16-rounded; error << threshold) ----
  {
    int r = t >> 5;                       // 0..15
    int c = (t & 31) * 16;                // 0..496 step 16
    int row = rowB0 + mT * 16 + r;
    const unsigned short* srcp = Bbf + (size_t)row * IN_DIM + c;
    uint4 u0 = *(const uint4*)srcp;
    uint4 u1 = *(const uint4*)(srcp + 8);
    float* dst = wnOut + (size_t)row * IN_DIM + c;
    float4 f;
    f.x = bf2f((unsigned short)(u0.x & 0xffff)); f.y = bf2f((unsigned short)(u0.x >> 16));
    f.z = bf2f((unsigned short)(u0.y & 0xffff)); f.w = bf2f((unsigned short)(u0.y >> 16));
    *(float4*)dst = f;
    f.x = bf2f((unsigned short)(u0.z & 0xffff)); f.y = bf2f((unsigned short)(u0.z >> 16));
    f.z = bf2f((unsigned short)(u0.w & 0xffff)); f.w = bf2f((unsigned short)(u0.w >> 16));
    *(float4*)(dst + 4) = f;
    f.x = bf2f((unsigned short)(u1.x & 0xffff)); f.y = bf2f((unsigned short)(u1.x >> 16));
    f.z = bf2f((unsigned short)(u1.y & 0xffff)); f.w = bf2f((unsigned short)(u1.y >> 16));
    *(float4*)(dst + 8) = f;
    f.x = bf2f((unsigned short)(u1.z & 0xffff)); f.y = bf2f((unsigned short)(u1.z >> 16));
    f.z = bf2f((unsigned short)(u1.w & 0xffff)); f.w = bf2f((unsigned short)(u1.w >> 16));
    *(float4*)(dst + 12) = f;
  }

  // ---- margin epilogue: out = rawdot except at (r, label[r]) ----
  float mm = mArr[0];
  float cm = cosf(mm), sm = sinf(mm);
  int rowb = rowA0 + wm * 32, colb = rowB0 + wn2 * 64;
#pragma unroll
  for (int m = 0; m < 2; ++m) {
#pragma unroll
    for (int q = 0; q < 4; ++q) {
      int R = rowb + m * 16 + sl * 4 + q;
      int lab = label[R];
      float nv = norms[R], fv = fixdot[R];
      float* orow = out0 + (size_t)R * OUT_DIM;
#pragma unroll
      for (int n = 0; n < 4; ++n) {
        int Cc = colb + n * 16 + rl;
        float val = acc[m][n][q];
        if (Cc == lab) {
          float c = fv / fmaxf(nv, EPSN);
          val = (c > 0.f) ? nv * (c * cm - sqrtf(fmaxf(1.f - c * c, 0.f)) * sm) : fv;
        }
        orow[Cc] = val;
      }
    }
  }
}

extern "C" void kernel_launch(void* const* d_in, const int* in_sizes, int n_in,
                              void* d_out, int out_size, void* d_ws, size_t ws_size,
                              hipStream_t stream) {
  const float* x = (const float*)d_in[0];
  const int* label = (const int*)d_in[1];
  const float* weight = (const float*)d_in[2];
  const float* mArr = (const float*)d_in[4];  // d_in[3] = s, unused by normfree output

  float* out0 = (float*)d_out;                               // [1024, 64000]
  float* wnOut = out0 + (size_t)B_ROWS * OUT_DIM;            // [64000, 512]

  char* ws = (char*)d_ws;
  float* norms = (float*)ws;                                 // 4 KiB
  float* fixdot = (float*)(ws + 4096);                       // 4 KiB
  unsigned short* xbf = (unsigned short*)(ws + 8192);        // 1 MiB
  unsigned short* wbf = (unsigned short*)(ws + 8192 + 2ull * B_ROWS * IN_DIM);  // 65.5 MiB

  prep_kernel<<<B_ROWS / 4, 256, 0, stream>>>(x, label, weight, norms, fixdot, xbf);
  wcast_kernel<<<OUT_DIM / 4, 256, 0, stream>>>(weight, wbf);
  gemm_epi_kernel<<<4000, 512, 0, stream>>>(xbf, wbf, norms, fixdot, label, mArr,
                                            out0, wnOut);
}

// Round 6
// 209.058 us; speedup vs baseline: 1.3610x; 1.1001x over previous
//
#include <hip/hip_runtime.h>
#include <cstdint>

#define EPSN 1e-12f
static constexpr int B_ROWS = 1024;
static constexpr int IN_DIM = 512;
static constexpr int OUT_DIM = 64000;

typedef __attribute__((ext_vector_type(8))) short bf16x8;
typedef __attribute__((ext_vector_type(4))) float f32x4;

__device__ __forceinline__ unsigned short f2bf(float f) {
  uint32_t u = __builtin_bit_cast(uint32_t, f);
  u += 0x7fffu + ((u >> 16) & 1u);   // round-to-nearest-even
  return (unsigned short)(u >> 16);
}

__device__ __forceinline__ float bf2f(unsigned short h) {
  uint32_t u = (uint32_t)h << 16;
  return __builtin_bit_cast(float, u);
}

__device__ __forceinline__ float wave_sum(float v) {
#pragma unroll
  for (int off = 32; off; off >>= 1) v += __shfl_xor(v, off);
  return v;
}

__device__ __forceinline__ void async16(const void* g, void* l) {
  __builtin_amdgcn_global_load_lds((const __attribute__((address_space(1))) uint32_t*)g,
                                   (__attribute__((address_space(3))) uint32_t*)l, 16, 0, 0);
}

// --- kernel 1: x-prep (norms + bf16 cast) + exact fixdot from RAW W ---
__global__ void prep_kernel(const float* __restrict__ X, const int* __restrict__ label,
                            const float* __restrict__ Wg, float* __restrict__ norms,
                            float* __restrict__ fixdot, unsigned short* __restrict__ xbf) {
  int lane = threadIdx.x & 63;
  int row = blockIdx.x * 4 + (threadIdx.x >> 6);
  const float* src = X + (size_t)row * IN_DIM + lane * 8;
  float4 a = *(const float4*)src;
  float4 b = *(const float4*)(src + 4);
  uint4 u;
  u.x = (uint32_t)f2bf(a.x) | ((uint32_t)f2bf(a.y) << 16);
  u.y = (uint32_t)f2bf(a.z) | ((uint32_t)f2bf(a.w) << 16);
  u.z = (uint32_t)f2bf(b.x) | ((uint32_t)f2bf(b.y) << 16);
  u.w = (uint32_t)f2bf(b.z) | ((uint32_t)f2bf(b.w) << 16);
  *(uint4*)(xbf + (size_t)row * IN_DIM + lane * 8) = u;
  float ssx = a.x * a.x;
  ssx = fmaf(a.y, a.y, ssx); ssx = fmaf(a.z, a.z, ssx); ssx = fmaf(a.w, a.w, ssx);
  ssx = fmaf(b.x, b.x, ssx); ssx = fmaf(b.y, b.y, ssx); ssx = fmaf(b.z, b.z, ssx);
  ssx = fmaf(b.w, b.w, ssx);
  int lab = label[row];
  const float* wsrc = Wg + (size_t)lab * IN_DIM + lane * 8;
  float4 wa = *(const float4*)wsrc, wb = *(const float4*)(wsrc + 4);
  float d = a.x * wa.x;
  d = fmaf(a.y, wa.y, d); d = fmaf(a.z, wa.z, d); d = fmaf(a.w, wa.w, d);
  d = fmaf(b.x, wb.x, d); d = fmaf(b.y, wb.y, d); d = fmaf(b.z, wb.z, d);
  d = fmaf(b.w, wb.w, d);
  float ssw = wa.x * wa.x;
  ssw = fmaf(wa.y, wa.y, ssw); ssw = fmaf(wa.z, wa.z, ssw); ssw = fmaf(wa.w, wa.w, ssw);
  ssw = fmaf(wb.x, wb.x, ssw); ssw = fmaf(wb.y, wb.y, ssw); ssw = fmaf(wb.z, wb.z, ssw);
  ssw = fmaf(wb.w, wb.w, ssw);
  ssx = wave_sum(ssx);
  d = wave_sum(d);
  ssw = wave_sum(ssw);
  if (lane == 0) {
    norms[row] = sqrtf(ssx);
    fixdot[row] = d / fmaxf(sqrtf(ssw), EPSN);   // = x . wn[lab], exact f32
  }
}

// --- kernel 2: W -> normalized bf16 (wbf) only; wn f32 written by GEMM epilogue ---
__global__ void wcast_kernel(const float* __restrict__ Wg, unsigned short* __restrict__ wbf) {
  int lane = threadIdx.x & 63;
  int row = blockIdx.x * 4 + (threadIdx.x >> 6);
  const float* src = Wg + (size_t)row * IN_DIM + lane * 8;
  float4 a = *(const float4*)src;
  float4 b = *(const float4*)(src + 4);
  float ss = a.x * a.x;
  ss = fmaf(a.y, a.y, ss); ss = fmaf(a.z, a.z, ss); ss = fmaf(a.w, a.w, ss);
  ss = fmaf(b.x, b.x, ss); ss = fmaf(b.y, b.y, ss); ss = fmaf(b.z, b.z, ss);
  ss = fmaf(b.w, b.w, ss);
  ss = wave_sum(ss);
  float inv = 1.0f / fmaxf(sqrtf(ss), EPSN);
  uint4 u;
  u.x = (uint32_t)f2bf(a.x * inv) | ((uint32_t)f2bf(a.y * inv) << 16);
  u.y = (uint32_t)f2bf(a.z * inv) | ((uint32_t)f2bf(a.w * inv) << 16);
  u.z = (uint32_t)f2bf(b.x * inv) | ((uint32_t)f2bf(b.y * inv) << 16);
  u.w = (uint32_t)f2bf(b.z * inv) | ((uint32_t)f2bf(b.w * inv) << 16);
  *(uint4*)(wbf + (size_t)row * IN_DIM + lane * 8) = u;
}

// --- kernel 3: bf16 MFMA GEMM (M=1024,N=64000,K=512) + margin epilogue + wn write ---
// BM=BN=256, 8 waves (2Mx4N), per-wave C = 128x64 (acc[8][4]). 16 K-subs of 32.
// Ring-4 LDS (A 4x16K @0, B 4x16K @65536) = 128 KiB. Depth-3 counted vmcnt,
// SINGLE barrier per phase: {vmcnt(8/4/0) -> barrier -> issue gload(sig+3) ->
// 12 ds_read -> 32 MFMA}. Safety: wave w's ds_reads of sub s drain at the
// compiler's auto-lgkm(0) before its MFMA(s), which precedes w's arrival at
// BARRIER(s+1); gload(s+4) (slot s&3) is issued only after BARRIER(s+1).
__global__ __launch_bounds__(512, 2) void gemm_epi_kernel(
    const unsigned short* __restrict__ Abf, const unsigned short* __restrict__ Bbf,
    const float* __restrict__ norms, const float* __restrict__ fixdot,
    const int* __restrict__ label, const float* __restrict__ mArr,
    float* __restrict__ out0, float* __restrict__ wnOut) {
  __shared__ char smem[131072];

  const int t = threadIdx.x;
  int flat = blockIdx.x;          // 1000 = 8 * 125, bijective XCD swizzle
  int xcd = flat & 7;
  int wk = (flat >> 3) + xcd * 125;
  int mT = wk & 3, nT = wk >> 2;  // 4 mT siblings per nT consecutive on one XCD
  int rowA0 = mT * 256, rowB0 = nT * 256;

  int lane = t & 63;
  int wid = t >> 6;
  int wm = wid >> 2, wn2 = wid & 3;   // 2M x 4N wave grid
  int rl = lane & 15, sl = lane >> 4;

  // staging chunk map (inverse swizzle): chunk c -> row r = c>>2, 16B-slot q
  int r0 = t >> 2, q0 = (t & 3) ^ ((r0 >> 1) & 3);
  int r1 = (t + 512) >> 2, q1 = ((t + 512) & 3) ^ ((r1 >> 1) & 3);
  const unsigned short* aP0 = Abf + (size_t)(rowA0 + r0) * IN_DIM + q0 * 8;
  const unsigned short* aP1 = Abf + (size_t)(rowA0 + r1) * IN_DIM + q1 * 8;
  const unsigned short* bP0 = Bbf + (size_t)(rowB0 + r0) * IN_DIM + q0 * 8;
  const unsigned short* bP1 = Bbf + (size_t)(rowB0 + r1) * IN_DIM + q1 * 8;

  auto issueSub = [&](int sig) {
    int kcol = sig * 32;
    char* aD = smem + (sig & 3) * 16384;
    char* bD = smem + 65536 + (sig & 3) * 16384;
    async16(aP0 + kcol, aD + t * 16);
    async16(aP1 + kcol, aD + (t + 512) * 16);
    async16(bP0 + kcol, bD + t * 16);
    async16(bP1 + kcol, bD + (t + 512) * 16);
  };

  issueSub(0); issueSub(1); issueSub(2);   // depth-3 prologue (12 outstanding)

  f32x4 acc[8][4];
#pragma unroll
  for (int m = 0; m < 8; ++m)
#pragma unroll
    for (int n = 0; n < 4; ++n) acc[m][n] = (f32x4){0.f, 0.f, 0.f, 0.f};

#pragma unroll 1
  for (int sigma = 0; sigma < 16; ++sigma) {
    __builtin_amdgcn_sched_barrier(0);
    if (sigma <= 13)      asm volatile("s_waitcnt vmcnt(8)" ::: "memory");
    else if (sigma == 14) asm volatile("s_waitcnt vmcnt(4)" ::: "memory");
    else                  asm volatile("s_waitcnt vmcnt(0)" ::: "memory");
    __builtin_amdgcn_s_barrier();
    __builtin_amdgcn_sched_barrier(0);
    if (sigma + 3 <= 15) issueSub(sigma + 3);   // AFTER barrier (slot-reuse proof)

    const char* aB = smem + (sigma & 3) * 16384;
    const char* bB = smem + 65536 + (sigma & 3) * 16384;
    bf16x8 av[8], bv[4];
#pragma unroll
    for (int m = 0; m < 8; ++m) {
      int r = wm * 128 + m * 16 + rl;
      av[m] = *(const bf16x8*)(aB + r * 64 + ((sl ^ ((r >> 1) & 3)) * 16));
    }
#pragma unroll
    for (int n = 0; n < 4; ++n) {
      int r = wn2 * 64 + n * 16 + rl;
      bv[n] = *(const bf16x8*)(bB + r * 64 + ((sl ^ ((r >> 1) & 3)) * 16));
    }
    __builtin_amdgcn_s_setprio(1);
#pragma unroll
    for (int n = 0; n < 4; ++n)
#pragma unroll
      for (int m = 0; m < 8; ++m)
        acc[m][n] = __builtin_amdgcn_mfma_f32_16x16x32_bf16(av[m], bv[n], acc[m][n], 0, 0, 0);
    __builtin_amdgcn_s_setprio(0);
    // no end-of-phase barrier: next phase's top barrier + auto-lgkm cover hazards
  }

  // ---- wn f32 output: each mT-sibling writes 64 rows of panel nT from L2-hot
  // wbf (bf16-rounded; error << threshold). 512 thr: row = t>>3, col-chunk t&7.
  {
    int r = t >> 3;                      // 0..63
    int c0 = (t & 7) * 64;               // 64 floats per thread
    int row = rowB0 + mT * 64 + r;
    const unsigned short* srcp = Bbf + (size_t)row * IN_DIM + c0;
    float* dst = wnOut + (size_t)row * IN_DIM + c0;
#pragma unroll
    for (int g = 0; g < 8; ++g) {
      uint4 uu = *(const uint4*)(srcp + g * 8);
      float4 f;
      f.x = bf2f((unsigned short)(uu.x & 0xffff)); f.y = bf2f((unsigned short)(uu.x >> 16));
      f.z = bf2f((unsigned short)(uu.y & 0xffff)); f.w = bf2f((unsigned short)(uu.y >> 16));
      *(float4*)(dst + g * 8) = f;
      f.x = bf2f((unsigned short)(uu.z & 0xffff)); f.y = bf2f((unsigned short)(uu.z >> 16));
      f.z = bf2f((unsigned short)(uu.w & 0xffff)); f.w = bf2f((unsigned short)(uu.w >> 16));
      *(float4*)(dst + g * 8 + 4) = f;
    }
  }

  // ---- margin epilogue: out = rawdot except at (r, label[r]) ----
  float mm = mArr[0];
  float cm = cosf(mm), sm = sinf(mm);
  int rowb = rowA0 + wm * 128, colb = rowB0 + wn2 * 64;
#pragma unroll
  for (int m = 0; m < 8; ++m) {
#pragma unroll
    for (int q = 0; q < 4; ++q) {
      int R = rowb + m * 16 + sl * 4 + q;
      int lab = label[R];
      float nv = norms[R], fv = fixdot[R];
      float* orow = out0 + (size_t)R * OUT_DIM;
#pragma unroll
      for (int n = 0; n < 4; ++n) {
        int Cc = colb + n * 16 + rl;
        float val = acc[m][n][q];
        if (Cc == lab) {
          float c = fv / fmaxf(nv, EPSN);
          val = (c > 0.f) ? nv * (c * cm - sqrtf(fmaxf(1.f - c * c, 0.f)) * sm) : fv;
        }
        orow[Cc] = val;
      }
    }
  }
}

extern "C" void kernel_launch(void* const* d_in, const int* in_sizes, int n_in,
                              void* d_out, int out_size, void* d_ws, size_t ws_size,
                              hipStream_t stream) {
  const float* x = (const float*)d_in[0];
  const int* label = (const int*)d_in[1];
  const float* weight = (const float*)d_in[2];
  const float* mArr = (const float*)d_in[4];  // d_in[3] = s, unused by normfree output

  float* out0 = (float*)d_out;                               // [1024, 64000]
  float* wnOut = out0 + (size_t)B_ROWS * OUT_DIM;            // [64000, 512]

  char* ws = (char*)d_ws;
  float* norms = (float*)ws;                                 // 4 KiB
  float* fixdot = (float*)(ws + 4096);                       // 4 KiB
  unsigned short* xbf = (unsigned short*)(ws + 8192);        // 1 MiB
  unsigned short* wbf = (unsigned short*)(ws + 8192 + 2ull * B_ROWS * IN_DIM);  // 65.5 MiB

  prep_kernel<<<B_ROWS / 4, 256, 0, stream>>>(x, label, weight, norms, fixdot, xbf);
  wcast_kernel<<<OUT_DIM / 4, 256, 0, stream>>>(weight, wbf);
  gemm_epi_kernel<<<1000, 512, 0, stream>>>(xbf, wbf, norms, fixdot, label, mArr,
                                            out0, wnOut);
}